// Round 11
// baseline (753.156 us; speedup 1.0000x reference)
//
#include <hip/hip_runtime.h>
#include <hip/hip_bf16.h>

// GCN forward on MI355X.
//   S1t  = (feat @ W1)^T   bf16 [HID][KP] swz       (gemm1: A=W1t, B=featb, DMA)
//   x1   = relu(adj @ S1 + b1)  split-K=2 fp32 partials -> relu_bias_fin
//   S2t  = (x1 @ W2)^T     bf16 [CLS][KP] swz       (gemm3, DMA)
//   x2   = adj @ S2        split-K=4 partials -> logsoftmax_fin
//
// History: R6/R8/R9 neutral; R12 (drop cvt_adj, fp32-A reg-staged swizzled)
// -23us = byte-proportional at ~6.3 TB/s => pipeline tracks the HBM byte
// model; adj-GEMMs are BW-bound. ~490us of dur_us is harness poison fill
// (2 x 245us, 1.6GB each) we cannot touch; ours ~247us vs ~154us byte floor.
// R13: cut cuttable bytes + launches:
//   - split-K 4->2 (GEMM2), 8->4 (GEMM4): part traffic 123->62 MB
//   - memsets deleted: EPI0 epilogue writes 0 for gcol>=Nn (grid covers all
//     KP cols); poison rows >=10000 of featb/x1b only reach zero-written or
//     guarded outputs (incl. NaN poison: those acc elems are discarded)
//   - 3 cvt kernels fused into 1 (branch on blockIdx range)
//   13 -> 7 dispatches.
// R14/R15/R16: resubmits (acquisition timeouts; never measured).

#define NROW 10000
#define FIN  512
#define HID  256
#define NCLS 64
#define KP   10048          // NROW rounded up to 64
#define KSPLIT2 2
#define KSPAN2  5056        // z0:[0,5056) z1:[5056,10048) both %64==0
#define KSPLIT4 4
#define KSPAN4  2560

typedef __bf16 bf8_t __attribute__((ext_vector_type(8)));
typedef __bf16 bf4_t __attribute__((ext_vector_type(4)));
typedef float  f4_t  __attribute__((ext_vector_type(4)));

typedef __attribute__((address_space(3))) void       lds_void;
typedef const __attribute__((address_space(1))) void glb_void;

__device__ __forceinline__ void dma16(const void* g, void* l) {
    __builtin_amdgcn_global_load_lds((glb_void*)g, (lds_void*)l, 16, 0, 0);
}

// swizzled column index: within each 64-col group, 8-elem chunk c -> c^(r&7)
__device__ __forceinline__ int swzc(int k, int r) {
    return (k & ~63) | ((((k >> 3) & 7) ^ (r & 7)) << 3) | (k & 7);
}

// ---------------- fused converts (all write SWIZZLED bf16) ----------------
// blocks [0,5000): feat cvt; [5000,5512): W1 transpose; [5512,5576): W2.
#define FEAT_BLKS 5000
#define W1_BLKS   512
__global__ void cvt_all(const float* __restrict__ feat, const float* __restrict__ W1,
                        const float* __restrict__ W2, __bf16* __restrict__ featb,
                        __bf16* __restrict__ W1t, __bf16* __restrict__ W2t) {
    int b = blockIdx.x;
    if (b < FEAT_BLKS) {
        int i = (b * 256 + threadIdx.x) * 4;          // covers 10000*512 exactly
        f4_t v = *(const f4_t*)(feat + i);
        bf4_t o;
        o[0] = (__bf16)v[0]; o[1] = (__bf16)v[1]; o[2] = (__bf16)v[2]; o[3] = (__bf16)v[3];
        int row = i >> 9, k = i & (FIN - 1);          // FIN=512
        *(bf4_t*)(featb + (long)row * FIN + swzc(k, row)) = o;
    } else if (b < FEAT_BLKS + W1_BLKS) {
        int idx = (b - FEAT_BLKS) * 256 + threadIdx.x;   // < FIN*HID
        int k = idx / HID, n = idx % HID;
        W1t[(long)n * FIN + swzc(k, n)] = (__bf16)W1[idx];
    } else {
        int idx = (b - FEAT_BLKS - W1_BLKS) * 256 + threadIdx.x;  // < HID*NCLS
        int k = idx / NCLS, n = idx % NCLS;
        W2t[(long)n * HID + swzc(k, n)] = (__bf16)W2[idx];
    }
}

// ---------------- GEMM: D[M][Nn] = A[M][K] * Bt[Nn][K]^T ----------------
// BM = 64. B bf16 PRE-SWIZZLED, staged via global_load_lds.
// A: AF32=false -> bf16 pre-swizzled DMA; AF32=true -> fp32 reg-staged with
// cvt + swizzled ds_write (clamped addresses; B pad-K must be zero).
// Double-buffered LDS, 2-phase pipeline, one barrier per K-iter.
// EPI 0: store bf16 SWIZZLED to outB; pads gcol>=Nn written ZERO (replaces
//        host-side memset; grid.y*BN must cover the full ldo-extent).
// EPI 2: fp32 partial per z-slice (guarded).
template<int BN, bool AF32, int EPI>
__global__ void __launch_bounds__(256, (BN >= 128) ? 3 : 4)
gemm_bt(const void* __restrict__ Ap, const __bf16* __restrict__ Bt,
        int M, int Nn, int K, int Kclamp, int lda, int ldb, int kspan,
        float* __restrict__ outF, __bf16* __restrict__ outB,
        int ldo, long partStride)
{
    constexpr int BM = 64, BK = 64;
    constexpr int WM = BM / 2, WN = BN / 2;      // 2x2 waves
    constexpr int MI = WM / 16, NI = WN / 16;
    constexpr int ACALLS = BM / 32;              // 1KB DMA chunks per wave
    constexpr int BCALLS = BN / 32;
    constexpr int ASZ = BM * BK, BSZ = BN * BK;
    __shared__ __bf16 As[2 * ASZ];
    __shared__ __bf16 Bs[2 * BSZ];

    const int tid  = threadIdx.x;
    const int lane = tid & 63;
    const int wave = tid >> 6;
    const int wm = wave >> 1, wn = wave & 1;
    const int m0 = blockIdx.x * BM;
    const int n0 = blockIdx.y * BN;
    const int kbase = blockIdx.z * kspan;
    const int kend  = min(K, kbase + kspan);     // multiple of BK

    f4_t acc[MI][NI];
    #pragma unroll
    for (int i = 0; i < MI; i++)
        #pragma unroll
        for (int j = 0; j < NI; j++)
            acc[i][j] = f4_t{0.f, 0.f, 0.f, 0.f};

    const int lrow  = lane & 15;
    const int koff0 = (lane >> 4) * 8;
    const int l7    = lrow & 7;                  // == fragment row & 7

    // ---- hoisted staging pointers ----
    const __bf16* Brow[BCALLS];
    #pragma unroll
    for (int j = 0; j < BCALLS; ++j) {
        int c = wave + j * 4;
        Brow[j] = Bt + (long)(n0 + c * 8 + (lane >> 3)) * ldb + (lane & 7) * 8;
    }
    const __bf16* ArowB[ACALLS];
    const float*  ArowF[4];
    int Acol[4], AldsOff[4];
    if constexpr (AF32) {
        // 4 fp32 chunks/thread; row & col clamped (B pad-K zero => harmless).
        #pragma unroll
        for (int i = 0; i < 4; ++i) {
            int idx = tid + i * 256;
            int r = idx >> 4, c4 = idx & 15;
            ArowF[i] = (const float*)Ap + (long)min(m0 + r, M - 1) * lda;
            Acol[i] = c4 * 4;
            AldsOff[i] = r * BK + ((((c4 >> 1) ^ (r & 7)) << 3) | ((c4 & 1) * 4));
        }
    } else {
        #pragma unroll
        for (int j = 0; j < ACALLS; ++j) {
            int c = wave + j * 4;
            ArowB[j] = (const __bf16*)Ap + (long)(m0 + c * 8 + (lane >> 3)) * lda + (lane & 7) * 8;
        }
    }

    // ---- prologue: stage tile kbase into buf 0 ----
    if constexpr (AF32) {
        f4_t av[4];
        #pragma unroll
        for (int i = 0; i < 4; ++i)
            av[i] = *(const f4_t*)(ArowF[i] + min(kbase + Acol[i], Kclamp - 4));
        #pragma unroll
        for (int i = 0; i < 4; ++i) {
            bf4_t o;
            o[0] = (__bf16)av[i][0]; o[1] = (__bf16)av[i][1];
            o[2] = (__bf16)av[i][2]; o[3] = (__bf16)av[i][3];
            *(bf4_t*)&As[AldsOff[i]] = o;
        }
    } else {
        #pragma unroll
        for (int j = 0; j < ACALLS; ++j)
            dma16(ArowB[j] + kbase, &As[(wave + j * 4) * 512]);
    }
    #pragma unroll
    for (int j = 0; j < BCALLS; ++j)
        dma16(Brow[j] + kbase, &Bs[(wave + j * 4) * 512]);
    __syncthreads();

    // ---- 2-phase pipelined K-loop, one barrier per iter ----
    int cur = 0;
    for (int k0 = kbase; k0 < kend; k0 += BK) {
        const bool has_next = (k0 + BK < kend);
        const int nxt = cur ^ 1;
        f4_t av[4];
        // issue next tile's loads BEFORE compute (latency hides under MFMA)
        if (has_next) {
            if constexpr (AF32) {
                #pragma unroll
                for (int i = 0; i < 4; ++i)
                    av[i] = *(const f4_t*)(ArowF[i] + min(k0 + BK + Acol[i], Kclamp - 4));
            } else {
                #pragma unroll
                for (int j = 0; j < ACALLS; ++j)
                    dma16(ArowB[j] + (k0 + BK), &As[nxt * ASZ + (wave + j * 4) * 512]);
            }
            #pragma unroll
            for (int j = 0; j < BCALLS; ++j)
                dma16(Brow[j] + (k0 + BK), &Bs[nxt * BSZ + (wave + j * 4) * 512]);
        }

        // compute on current buffer; swizzled chunk reads (conflict-free)
        #pragma unroll
        for (int ks = 0; ks < BK; ks += 32) {
            const int cc = (ks + koff0) >> 3;          // original chunk idx
            const int co = ((cc ^ l7) << 3);           // swizzled byte-chunk off
            bf8_t af[MI], bfv[NI];
            #pragma unroll
            for (int mi = 0; mi < MI; mi++)
                af[mi] = *(const bf8_t*)&As[cur * ASZ + (wm * WM + mi * 16 + lrow) * BK + co];
            #pragma unroll
            for (int ni = 0; ni < NI; ni++)
                bfv[ni] = *(const bf8_t*)&Bs[cur * BSZ + (wn * WN + ni * 16 + lrow) * BK + co];
            #pragma unroll
            for (int mi = 0; mi < MI; mi++)
                #pragma unroll
                for (int ni = 0; ni < NI; ni++)
                    acc[mi][ni] = __builtin_amdgcn_mfma_f32_16x16x32_bf16(
                        af[mi], bfv[ni], acc[mi][ni], 0, 0, 0);
        }

        // write-late: A(k+1) cvt + swizzled ds_write into nxt (after compute)
        if (has_next) {
            if constexpr (AF32) {
                #pragma unroll
                for (int i = 0; i < 4; ++i) {
                    bf4_t o;
                    o[0] = (__bf16)av[i][0]; o[1] = (__bf16)av[i][1];
                    o[2] = (__bf16)av[i][2]; o[3] = (__bf16)av[i][3];
                    *(bf4_t*)&As[nxt * ASZ + AldsOff[i]] = o;
                }
            }
        }
        __syncthreads();   // drains DMA (vmcnt0) + ds_writes for nxt
        cur ^= 1;
    }

    // ---- epilogue ----  C/D layout: col = lane&15, row = (lane>>4)*4 + reg
    const int erow = wm * WM + (lane >> 4) * 4;
    const int ecol = wn * WN + lrow;
    #pragma unroll
    for (int mi = 0; mi < MI; mi++) {
        #pragma unroll
        for (int ni = 0; ni < NI; ni++) {
            #pragma unroll
            for (int r = 0; r < 4; r++) {
                int grow = m0 + erow + mi * 16 + r;
                int gcol = n0 + ecol + ni * 16;
                if constexpr (EPI == 0) {
                    // pads (gcol>=Nn) written ZERO: replaces host memset and
                    // quashes NaN/poison acc from unwritten B rows >= Nn.
                    if (grow < M) {
                        float v = (gcol < Nn) ? acc[mi][ni][r] : 0.f;
                        outB[(long)grow * ldo + swzc(gcol, grow)] = (__bf16)v;
                    }
                } else {
                    if (grow < M && gcol < Nn)
                        outF[blockIdx.z * partStride + (long)grow * ldo + gcol] = acc[mi][ni][r];
                }
            }
        }
    }
}

// ---------------- GEMM2 reduce: x1 = relu(sum(part) + b1) ----------------
// outF (d_out) linear fp32; x1b bf16 SWIZZLED [row][HID].
__global__ void relu_bias_fin(const float* __restrict__ part, const float* __restrict__ b1,
                              float* __restrict__ outF, __bf16* __restrict__ outB) {
    long i = (long)(blockIdx.x * 256 + threadIdx.x) * 4;
    f4_t v = *(const f4_t*)(part + i);
    #pragma unroll
    for (int s = 1; s < KSPLIT2; s++) {
        f4_t p = *(const f4_t*)(part + (long)s * NROW * HID + i);
        v[0] += p[0]; v[1] += p[1]; v[2] += p[2]; v[3] += p[3];
    }
    int row = (int)(i >> 8);          // HID = 256
    int col = (int)(i & (HID - 1));
    f4_t b = *(const f4_t*)(b1 + col);
    f4_t y;
    bf4_t yb;
    #pragma unroll
    for (int j = 0; j < 4; j++) {
        y[j] = fmaxf(v[j] + b[j], 0.f);
        yb[j] = (__bf16)y[j];
    }
    *(f4_t*)(outF + i) = y;
    *(bf4_t*)(outB + (long)row * HID + swzc(col, row)) = yb;
}

// ---------------- split-K reduce + bias + log_softmax ----------------
__global__ void logsoftmax_fin(const float* __restrict__ part, const float* __restrict__ b2,
                               float* __restrict__ out, int M) {
    int row  = blockIdx.x * 4 + (threadIdx.x >> 6);
    int lane = threadIdx.x & 63;
    if (row >= M) return;
    float v = b2[lane];
    #pragma unroll
    for (int s = 0; s < KSPLIT4; s++) v += part[((long)s * M + row) * NCLS + lane];
    float m = v;
    #pragma unroll
    for (int off = 32; off > 0; off >>= 1) m = fmaxf(m, __shfl_xor(m, off));
    float e = __expf(v - m);
    float sum = e;
    #pragma unroll
    for (int off = 32; off > 0; off >>= 1) sum += __shfl_xor(sum, off);
    out[(long)row * NCLS + lane] = (v - m) - __logf(sum);
}

extern "C" void kernel_launch(void* const* d_in, const int* in_sizes, int n_in,
                              void* d_out, int out_size, void* d_ws, size_t ws_size,
                              hipStream_t stream) {
    const float* feat = (const float*)d_in[0];
    const float* adj  = (const float*)d_in[1];
    const float* W1   = (const float*)d_in[2];
    const float* b1   = (const float*)d_in[3];
    const float* W2   = (const float*)d_in[4];
    const float* b2   = (const float*)d_in[5];
    float* out = (float*)d_out;
    char* ws = (char*)d_ws;

    // workspace layout (256B aligned) -- ~43 MB (all bf16 bufs swizzled)
    __bf16* featb = (__bf16*)(ws);                    // [10048][FIN]  10,289,152
    __bf16* W1t   = (__bf16*)(ws + 10289152);         // [HID][FIN]       262,144
    __bf16* W2t   = (__bf16*)(ws + 10551296);         // [CLS][HID]        32,768
    __bf16* S1t   = (__bf16*)(ws + 10584064);         // [HID][KP]      5,144,576
    __bf16* x1b   = (__bf16*)(ws + 15728640);         // [10048][HID]   5,144,576
    __bf16* S2t   = (__bf16*)(ws + 20873216);         // [CLS][KP]      1,286,144
    float*  part  = (float*) (ws + 22159360);         // [2][N][HID] fp32

    // fused converts (feat + W1 + W2), 1 launch
    cvt_all<<<FEAT_BLKS + W1_BLKS + 64, 256, 0, stream>>>(feat, W1, W2, featb, W1t, W2t);

    // S1t[HID][n] = W1t @ featb^T   (M=256, Nn=NROW, K=FIN); pads zero-written
    gemm_bt<64, false, 0><<<dim3(4, 157, 1), 256, 0, stream>>>(
        W1t, featb, HID, NROW, FIN, FIN, FIN, FIN, FIN,
        nullptr, S1t, KP, 0);

    // x1 partials = adj @ S1   (M=NROW, Nn=HID, K=KP, split-K=2, fp32-A)
    gemm_bt<128, true, 2><<<dim3(157, 2, KSPLIT2), 256, 0, stream>>>(
        adj, S1t, NROW, HID, KP, NROW, NROW, KP, KSPAN2,
        part, nullptr, HID, (long)NROW * HID);

    // x1 = relu(sum + b1) -> out fp32, x1b bf16 swz
    relu_bias_fin<<<NROW * HID / 4 / 256, 256, 0, stream>>>(part, b1, out, x1b);

    // S2t[CLS][n] = W2t @ x1b^T  (M=64, Nn=NROW, K=HID); pads zero-written
    gemm_bt<64, false, 0><<<dim3(1, 157, 1), 256, 0, stream>>>(
        W2t, x1b, NCLS, NROW, HID, HID, HID, HID, HID,
        nullptr, S2t, KP, 0);

    // x2 partials = adj @ S2   (M=NROW, Nn=NCLS, K=KP, split-K=4, fp32-A)
    gemm_bt<64, true, 2><<<dim3(157, 1, KSPLIT4), 256, 0, stream>>>(
        adj, S2t, NROW, NCLS, KP, NROW, NROW, KP, KSPAN4,
        part, nullptr, NCLS, (long)NROW * NCLS);

    // reduce + b2 + log_softmax -> second output
    logsoftmax_fin<<<2500, 256, 0, stream>>>(part, b2, out + (long)NROW * HID, NROW);
}